// Round 1
// baseline (3987.989 us; speedup 1.0000x reference)
//
#include <hip/hip_runtime.h>
#include <hip/hip_bf16.h>

#define NN 100000
#define NE 640000
#define DD 128
#define NG 64
#define NL 3
#define BN_EPS 1e-5f

__device__ __forceinline__ void atomAddG(float* p, float v) { unsafeAtomicAdd(p, v); }

// ---------------- degree / norm ----------------
__global__ void k_deg(const int* __restrict__ dst, float* __restrict__ deg) {
    int e = blockIdx.x * 256 + threadIdx.x;
    if (e < NE) atomAddG(&deg[dst[e]], 1.0f);
}

__global__ void k_dinv(float* __restrict__ deg) {
    int i = blockIdx.x * 256 + threadIdx.x;
    if (i < NN) { float d = deg[i]; deg[i] = d > 0.f ? rsqrtf(d) : 0.f; }
}

__global__ void k_norm(const int* __restrict__ src, const int* __restrict__ dst,
                       const float* __restrict__ dinv, float* __restrict__ nrm) {
    int e = blockIdx.x * 256 + threadIdx.x;
    if (e < NE) nrm[e] = dinv[src[e]] * dinv[dst[e]];
}

// ---------------- GEMM [rows,128] @ [128,128] (+bias) ----------------
// MODE 0: plain (no bias needed for conv: BN absorbs it)
// MODE 1: +bias, accumulate per-channel sum/sumsq for BN stats
// MODE 2: +bias, apply relu(a*scl+shf) to A elements while staging (fused BN+ReLU)
template <int MODE>
__global__ __launch_bounds__(256) void k_gemm(
    const float* __restrict__ A, const float* __restrict__ W,
    const float* __restrict__ bias, float* __restrict__ C,
    const float* __restrict__ scl, const float* __restrict__ shf,
    float* __restrict__ sSum, float* __restrict__ sSq)
{
    __shared__ float lw[128 * 128];   // W[k][c]
    __shared__ float lx[32 * 128];    // A tile
    int tid = threadIdx.x;
    int row0 = blockIdx.x * 32;

    // stage W (16384 floats = 4096 float4)
#pragma unroll
    for (int j = 0; j < 16; ++j) {
        int f = (tid + j * 256) * 4;
        *(float4*)(lw + f) = *(const float4*)(W + f);
    }
    // stage A tile (4096 floats = 1024 float4)
#pragma unroll
    for (int j = 0; j < 4; ++j) {
        int f = (tid + j * 256) * 4;
        int r = f >> 7, c = f & 127;
        float4 v = *(const float4*)(A + (size_t)(row0 + r) * DD + c);
        if (MODE == 2) {
            float4 sv = *(const float4*)(scl + c);
            float4 fv = *(const float4*)(shf + c);
            v.x = fmaxf(0.f, v.x * sv.x + fv.x);
            v.y = fmaxf(0.f, v.y * sv.y + fv.y);
            v.z = fmaxf(0.f, v.z * sv.z + fv.z);
            v.w = fmaxf(0.f, v.w * sv.w + fv.w);
        }
        *(float4*)(lx + r * DD + c) = v;
    }
    __syncthreads();

    int ct = tid & 15, rt = tid >> 4;
    int c0 = ct * 8, r0 = rt * 2;
    float acc0[8], acc1[8];
#pragma unroll
    for (int j = 0; j < 8; ++j) { acc0[j] = 0.f; acc1[j] = 0.f; }

    const float* xr0 = lx + r0 * DD;
    const float* xr1 = lx + (r0 + 1) * DD;
#pragma unroll 2
    for (int k = 0; k < 128; k += 4) {
        float a0[4], a1[4];
        *(float4*)a0 = *(const float4*)(xr0 + k);
        *(float4*)a1 = *(const float4*)(xr1 + k);
#pragma unroll
        for (int kk = 0; kk < 4; ++kk) {
            float w[8];
            *(float4*)w       = *(const float4*)(lw + (k + kk) * DD + c0);
            *(float4*)(w + 4) = *(const float4*)(lw + (k + kk) * DD + c0 + 4);
#pragma unroll
            for (int j = 0; j < 8; ++j) {
                acc0[j] = fmaf(a0[kk], w[j], acc0[j]);
                acc1[j] = fmaf(a1[kk], w[j], acc1[j]);
            }
        }
    }

    float bc[8];
    if (bias) {
        *(float4*)bc       = *(const float4*)(bias + c0);
        *(float4*)(bc + 4) = *(const float4*)(bias + c0 + 4);
    } else {
#pragma unroll
        for (int j = 0; j < 8; ++j) bc[j] = 0.f;
    }
#pragma unroll
    for (int j = 0; j < 8; ++j) { acc0[j] += bc[j]; acc1[j] += bc[j]; }

    *(float4*)(C + (size_t)(row0 + r0) * DD + c0)         = *(float4*)acc0;
    *(float4*)(C + (size_t)(row0 + r0) * DD + c0 + 4)     = *(float4*)(acc0 + 4);
    *(float4*)(C + (size_t)(row0 + r0 + 1) * DD + c0)     = *(float4*)acc1;
    *(float4*)(C + (size_t)(row0 + r0 + 1) * DD + c0 + 4) = *(float4*)(acc1 + 4);

    if (MODE == 1) {
        __syncthreads();                 // done reading lw; reuse for reduction
        float* ls = lw;
        float* lq = lw + 128;
        if (tid < 128) { ls[tid] = 0.f; lq[tid] = 0.f; }
        __syncthreads();
#pragma unroll
        for (int j = 0; j < 8; ++j) {
            atomicAdd(&ls[c0 + j], acc0[j] + acc1[j]);
            atomicAdd(&lq[c0 + j], acc0[j] * acc0[j] + acc1[j] * acc1[j]);
        }
        __syncthreads();
        if (tid < 128) { atomAddG(&sSum[tid], ls[tid]); atomAddG(&sSq[tid], lq[tid]); }
    }
}

// ---------------- BN finalize: scale/shift ----------------
__global__ void k_bnfinal(const float* __restrict__ sSum, const float* __restrict__ sSq,
                          const float* __restrict__ g, const float* __restrict__ be,
                          float* __restrict__ scl, float* __restrict__ shf) {
    int c = threadIdx.x;
    float m = sSum[c] * (1.0f / NN);
    float v = sSq[c] * (1.0f / NN) - m * m;
    float inv = rsqrtf(v + BN_EPS);
    float s = g[c] * inv;
    scl[c] = s;
    shf[c] = be[c] - m * s;
}

// ---------------- column stats over [NN,128] ----------------
__global__ __launch_bounds__(256) void k_colstats(const float* __restrict__ A,
                                                  float* __restrict__ sSum, float* __restrict__ sSq) {
    __shared__ float ls[256], lq[256];
    int tid = threadIdx.x;
    int c = tid & 127, half = tid >> 7;
    int rend = min((int)(blockIdx.x + 1) * 128, NN);
    float s = 0.f, q = 0.f;
    for (int r = blockIdx.x * 128 + half; r < rend; r += 2) {
        float v = A[(size_t)r * DD + c];
        s += v; q += v * v;
    }
    ls[tid] = s; lq[tid] = q;
    __syncthreads();
    if (tid < 128) {
        atomAddG(&sSum[tid], ls[tid] + ls[tid + 128]);
        atomAddG(&sSq[tid],  lq[tid] + lq[tid + 128]);
    }
}

// ---------------- edge scatter: agg[dst] += hw[src]*norm ----------------
__global__ __launch_bounds__(256) void k_scatter(
    const float* __restrict__ hw, const float* __restrict__ nrm,
    const int* __restrict__ src, const int* __restrict__ dst,
    float* __restrict__ agg) {
    int t = blockIdx.x * 256 + threadIdx.x;
    int e = t >> 5;          // 8 edges / block
    int c4 = (t & 31) * 4;   // float4 lane
    float w = nrm[e];
    if (w != 0.f) {
        int s = src[e], d = dst[e];
        float4 v = *(const float4*)(hw + (size_t)s * DD + c4);
        float* p = agg + (size_t)d * DD + c4;
        atomAddG(p,     v.x * w);
        atomAddG(p + 1, v.y * w);
        atomAddG(p + 2, v.z * w);
        atomAddG(p + 3, v.w * w);
    }
}

// ---------------- residual update: h += relu(agg*scl+shf) ----------------
__global__ __launch_bounds__(256) void k_update(float* __restrict__ h, const float* __restrict__ agg,
                                                const float* __restrict__ scl, const float* __restrict__ shf) {
    int idx = (blockIdx.x * 256 + threadIdx.x) * 4;
    int c = idx & 127;
    float4 a = *(const float4*)(agg + idx);
    float4 hv = *(const float4*)(h + idx);
    float4 sv = *(const float4*)(scl + c);
    float4 fv = *(const float4*)(shf + c);
    hv.x += fmaxf(0.f, a.x * sv.x + fv.x);
    hv.y += fmaxf(0.f, a.y * sv.y + fv.y);
    hv.z += fmaxf(0.f, a.z * sv.z + fv.z);
    hv.w += fmaxf(0.f, a.w * sv.w + fv.w);
    *(float4*)(h + idx) = hv;
}

// ---------------- pooling (batch sorted: run-length accumulate) ----------------
__global__ __launch_bounds__(128) void k_pool(const float* __restrict__ h, const int* __restrict__ batch,
                                              float* __restrict__ hg) {
    int c = threadIdx.x;
    int r0 = blockIdx.x * 256;
    int rend = min(r0 + 256, NN);
    float acc = 0.f;
    int cur = batch[r0];
    for (int r = r0; r < rend; ++r) {
        int b = batch[r];
        if (b != cur) { atomAddG(&hg[cur * DD + c], acc); acc = 0.f; cur = b; }
        acc += h[(size_t)r * DD + c];
    }
    atomAddG(&hg[cur * DD + c], acc);
}

// ---------------- readout MLP 128->64->32->1 ----------------
__global__ __launch_bounds__(128) void k_readout(
    const float* __restrict__ hg,
    const float* __restrict__ W1, const float* __restrict__ b1,
    const float* __restrict__ W2, const float* __restrict__ b2,
    const float* __restrict__ W3, const float* __restrict__ b3,
    float* __restrict__ out) {
    __shared__ float a0[128], a1[64], a2[32];
    int g = blockIdx.x, t = threadIdx.x;
    a0[t] = hg[g * DD + t];
    __syncthreads();
    if (t < 64) {
        float s = b1[t];
        for (int k = 0; k < 128; ++k) s += a0[k] * W1[k * 64 + t];
        a1[t] = fmaxf(s, 0.f);
    }
    __syncthreads();
    if (t < 32) {
        float s = b2[t];
        for (int k = 0; k < 64; ++k) s += a1[k] * W2[k * 32 + t];
        a2[t] = fmaxf(s, 0.f);
    }
    __syncthreads();
    if (t == 0) {
        float s = b3[0];
        for (int k = 0; k < 32; ++k) s += a2[k] * W3[k];
        out[g] = s;
    }
}

extern "C" void kernel_launch(void* const* d_in, const int* in_sizes, int n_in,
                              void* d_out, int out_size, void* d_ws, size_t ws_size,
                              hipStream_t stream) {
    const float* x      = (const float*)d_in[0];
    const int*   ei     = (const int*)d_in[1];
    const int*   batch  = (const int*)d_in[2];
    const float* enc_W1 = (const float*)d_in[3];
    const float* enc_b1 = (const float*)d_in[4];
    const float* enc_g  = (const float*)d_in[5];
    const float* enc_be = (const float*)d_in[6];
    const float* enc_W2 = (const float*)d_in[7];
    const float* enc_b2 = (const float*)d_in[8];
    const float* conv_W = (const float*)d_in[9];
    // d_in[10] = conv_b: BN directly after conv absorbs additive bias -> unused
    const float* bn_g   = (const float*)d_in[11];
    const float* bn_b   = (const float*)d_in[12];
    const float* ro_W1  = (const float*)d_in[13];
    const float* ro_b1  = (const float*)d_in[14];
    const float* ro_W2  = (const float*)d_in[15];
    const float* ro_b2  = (const float*)d_in[16];
    const float* ro_W3  = (const float*)d_in[17];
    const float* ro_b3  = (const float*)d_in[18];

    const int* srcI = ei;
    const int* dstI = ei + NE;

    float* ws   = (float*)d_ws;
    float* h    = ws;                    // 12.8M
    float* t1   = ws + 12800000;         // 12.8M
    float* agg  = ws + 25600000;         // 12.8M
    float* nrm  = ws + 38400000;         // 640K
    float* deg  = ws + 39040000;         // 100K
    float* sSum = ws + 39140000;         // 128
    float* sSq  = sSum + 128;            // 128
    float* scl  = sSum + 256;            // 128
    float* shf  = sSum + 384;            // 128
    float* hg   = ws + 39140512;         // 8192

    // degree + norm
    hipMemsetAsync(deg, 0, NN * sizeof(float), stream);
    k_deg<<<2500, 256, 0, stream>>>(dstI, deg);
    k_dinv<<<391, 256, 0, stream>>>(deg);
    k_norm<<<2500, 256, 0, stream>>>(srcI, dstI, deg, nrm);

    // encoder: Linear -> BN -> ReLU -> Linear
    hipMemsetAsync(sSum, 0, 256 * sizeof(float), stream);
    k_gemm<1><<<3125, 256, 0, stream>>>(x, enc_W1, enc_b1, t1, nullptr, nullptr, sSum, sSq);
    k_bnfinal<<<1, 128, 0, stream>>>(sSum, sSq, enc_g, enc_be, scl, shf);
    k_gemm<2><<<3125, 256, 0, stream>>>(t1, enc_W2, enc_b2, h, scl, shf, nullptr, nullptr);

    // GCN layers
    for (int l = 0; l < NL; ++l) {
        k_gemm<0><<<3125, 256, 0, stream>>>(h, conv_W + (size_t)l * DD * DD, nullptr, t1,
                                            nullptr, nullptr, nullptr, nullptr);
        hipMemsetAsync(agg, 0, (size_t)NN * DD * sizeof(float), stream);
        k_scatter<<<80000, 256, 0, stream>>>(t1, nrm, srcI, dstI, agg);
        hipMemsetAsync(sSum, 0, 256 * sizeof(float), stream);
        k_colstats<<<782, 256, 0, stream>>>(agg, sSum, sSq);
        k_bnfinal<<<1, 128, 0, stream>>>(sSum, sSq, bn_g + l * DD, bn_b + l * DD, scl, shf);
        k_update<<<12500, 256, 0, stream>>>(h, agg, scl, shf);
    }

    // pooling + readout
    hipMemsetAsync(hg, 0, NG * DD * sizeof(float), stream);
    k_pool<<<391, 128, 0, stream>>>(h, batch, hg);
    k_readout<<<NG, 128, 0, stream>>>(hg, ro_W1, ro_b1, ro_W2, ro_b2, ro_W3, ro_b3, (float*)d_out);
}

// Round 2
// 964.057 us; speedup vs baseline: 4.1367x; 4.1367x over previous
//
#include <hip/hip_runtime.h>
#include <hip/hip_bf16.h>

#define NN 100000
#define NE 640000
#define DD 128
#define NG 64
#define NL 3
#define BN_EPS 1e-5f

typedef unsigned short u16;
typedef unsigned int u32;

__device__ __forceinline__ void atomAddG(float* p, float v) { unsafeAtomicAdd(p, v); }

// ---------------- CSR build ----------------
__global__ void k_degI(const int* __restrict__ dst, int* __restrict__ degI) {
    int e = blockIdx.x * 256 + threadIdx.x;
    if (e < NE) atomicAdd(&degI[dst[e]], 1);
}

__global__ void k_dinv(const int* __restrict__ degI, float* __restrict__ dinv) {
    int i = blockIdx.x * 256 + threadIdx.x;
    if (i < NN) { int d = degI[i]; dinv[i] = d > 0 ? rsqrtf((float)d) : 0.f; }
}

__global__ void k_scan1(const int* __restrict__ degI, int* __restrict__ offs, int* __restrict__ bsum) {
    __shared__ int ls[256];
    int t = threadIdx.x;
    int i = blockIdx.x * 256 + t;
    int v = (i < NN) ? degI[i] : 0;
    ls[t] = v;
    __syncthreads();
    for (int off = 1; off < 256; off <<= 1) {
        int u = (t >= off) ? ls[t - off] : 0;
        __syncthreads();
        ls[t] += u;
        __syncthreads();
    }
    if (i < NN) offs[i] = ls[t] - v;   // exclusive
    if (t == 255) bsum[blockIdx.x] = ls[255];
}

__global__ void k_scan2(int* __restrict__ bsum, int nb) {
    __shared__ int ls[512];
    int t = threadIdx.x;
    int v = (t < nb) ? bsum[t] : 0;
    ls[t] = v;
    __syncthreads();
    for (int off = 1; off < 512; off <<= 1) {
        int u = (t >= off) ? ls[t - off] : 0;
        __syncthreads();
        ls[t] += u;
        __syncthreads();
    }
    if (t < nb) bsum[t] = ls[t] - v;   // exclusive
}

__global__ void k_scan3(int* __restrict__ offs, const int* __restrict__ bsum) {
    int i = blockIdx.x * 256 + threadIdx.x;
    if (i < NN) offs[i] += bsum[blockIdx.x];
    if (i == 0) offs[NN] = NE;
}

// counting-sort placement: eRec[pos] = {src, bits(dinv[src])}
__global__ void k_place(const int* __restrict__ src, const int* __restrict__ dst,
                        const int* __restrict__ offs, int* __restrict__ cur,
                        const float* __restrict__ dinv, int2* __restrict__ eRec) {
    int e = blockIdx.x * 256 + threadIdx.x;
    if (e < NE) {
        int d = dst[e], s = src[e];
        int pos = offs[d] + atomicAdd(&cur[d], 1);
        eRec[pos] = make_int2(s, __float_as_int(dinv[s]));
    }
}

// ---------------- GEMM [rows,128] @ [128,128] (+bias) ----------------
// MODE 0: plain; MODE 1: +bias, BN stats; MODE 2: +bias, relu(a*scl+shf) on A load
// OUTB: store C as bf16
template <int MODE, bool OUTB>
__global__ __launch_bounds__(256) void k_gemm(
    const float* __restrict__ A, const float* __restrict__ W,
    const float* __restrict__ bias, void* __restrict__ Cv,
    const float* __restrict__ scl, const float* __restrict__ shf,
    float* __restrict__ sSum, float* __restrict__ sSq)
{
    __shared__ float lw[128 * 128];
    __shared__ float lx[32 * 128];
    int tid = threadIdx.x;
    int row0 = blockIdx.x * 32;

#pragma unroll
    for (int j = 0; j < 16; ++j) {
        int f = (tid + j * 256) * 4;
        *(float4*)(lw + f) = *(const float4*)(W + f);
    }
#pragma unroll
    for (int j = 0; j < 4; ++j) {
        int f = (tid + j * 256) * 4;
        int r = f >> 7, c = f & 127;
        float4 v = *(const float4*)(A + (size_t)(row0 + r) * DD + c);
        if (MODE == 2) {
            float4 sv = *(const float4*)(scl + c);
            float4 fv = *(const float4*)(shf + c);
            v.x = fmaxf(0.f, v.x * sv.x + fv.x);
            v.y = fmaxf(0.f, v.y * sv.y + fv.y);
            v.z = fmaxf(0.f, v.z * sv.z + fv.z);
            v.w = fmaxf(0.f, v.w * sv.w + fv.w);
        }
        *(float4*)(lx + r * DD + c) = v;
    }
    __syncthreads();

    int ct = tid & 15, rt = tid >> 4;
    int c0 = ct * 8, r0 = rt * 2;
    float acc0[8], acc1[8];
#pragma unroll
    for (int j = 0; j < 8; ++j) { acc0[j] = 0.f; acc1[j] = 0.f; }

    const float* xr0 = lx + r0 * DD;
    const float* xr1 = lx + (r0 + 1) * DD;
#pragma unroll 2
    for (int k = 0; k < 128; k += 4) {
        float a0[4], a1[4];
        *(float4*)a0 = *(const float4*)(xr0 + k);
        *(float4*)a1 = *(const float4*)(xr1 + k);
#pragma unroll
        for (int kk = 0; kk < 4; ++kk) {
            float w[8];
            *(float4*)w       = *(const float4*)(lw + (k + kk) * DD + c0);
            *(float4*)(w + 4) = *(const float4*)(lw + (k + kk) * DD + c0 + 4);
#pragma unroll
            for (int j = 0; j < 8; ++j) {
                acc0[j] = fmaf(a0[kk], w[j], acc0[j]);
                acc1[j] = fmaf(a1[kk], w[j], acc1[j]);
            }
        }
    }

    if (MODE == 1 || MODE == 2) {
        float bc[8];
        *(float4*)bc       = *(const float4*)(bias + c0);
        *(float4*)(bc + 4) = *(const float4*)(bias + c0 + 4);
#pragma unroll
        for (int j = 0; j < 8; ++j) { acc0[j] += bc[j]; acc1[j] += bc[j]; }
    }

    if (OUTB) {
        u16* Cb = (u16*)Cv;
        u16 t0[8], t1v[8];
#pragma unroll
        for (int j = 0; j < 8; ++j) {
            __hip_bfloat16 b0 = __float2bfloat16(acc0[j]);
            __hip_bfloat16 b1 = __float2bfloat16(acc1[j]);
            t0[j] = *(u16*)&b0; t1v[j] = *(u16*)&b1;
        }
        *(uint4*)(Cb + (size_t)(row0 + r0) * DD + c0)     = *(uint4*)t0;
        *(uint4*)(Cb + (size_t)(row0 + r0 + 1) * DD + c0) = *(uint4*)t1v;
    } else {
        float* C = (float*)Cv;
        *(float4*)(C + (size_t)(row0 + r0) * DD + c0)         = *(float4*)acc0;
        *(float4*)(C + (size_t)(row0 + r0) * DD + c0 + 4)     = *(float4*)(acc0 + 4);
        *(float4*)(C + (size_t)(row0 + r0 + 1) * DD + c0)     = *(float4*)acc1;
        *(float4*)(C + (size_t)(row0 + r0 + 1) * DD + c0 + 4) = *(float4*)(acc1 + 4);
    }

    if (MODE == 1) {
        __syncthreads();
        float* ls = lw;
        float* lq = lw + 128;
        if (tid < 128) { ls[tid] = 0.f; lq[tid] = 0.f; }
        __syncthreads();
#pragma unroll
        for (int j = 0; j < 8; ++j) {
            atomicAdd(&ls[c0 + j], acc0[j] + acc1[j]);
            atomicAdd(&lq[c0 + j], acc0[j] * acc0[j] + acc1[j] * acc1[j]);
        }
        __syncthreads();
        if (tid < 128) { atomAddG(&sSum[tid], ls[tid]); atomAddG(&sSq[tid], lq[tid]); }
    }
}

// ---------------- BN finalize ----------------
__global__ void k_bnfinal(const float* __restrict__ sSum, const float* __restrict__ sSq,
                          const float* __restrict__ g, const float* __restrict__ be,
                          float* __restrict__ scl, float* __restrict__ shf) {
    int c = threadIdx.x;
    float m = sSum[c] * (1.0f / NN);
    float v = sSq[c] * (1.0f / NN) - m * m;
    float s = g[c] * rsqrtf(v + BN_EPS);
    scl[c] = s;
    shf[c] = be[c] - m * s;
}

// ---------------- CSR pull aggregation + fused BN stats ----------------
// agg[d,:] = dinv[d] * sum_{e: dst=d} dinv[src_e] * hw_bf16[src_e,:]
__global__ __launch_bounds__(256) void k_agg(
    const u32* __restrict__ hwb,          // bf16x2 rows [NN][64]
    const int2* __restrict__ eRec, const int* __restrict__ offs,
    const float* __restrict__ dinv,
    float* __restrict__ agg, float* __restrict__ sSum, float* __restrict__ sSq)
{
    int tid = threadIdx.x;
    int lane = tid & 63;
    int wav = tid >> 6;
    int gw = blockIdx.x * 4 + wav;
    int nw = gridDim.x * 4;
    float sx0 = 0.f, sx1 = 0.f, sq0 = 0.f, sq1 = 0.f;
    float2* agg2 = (float2*)agg;

    for (int d = gw; d < NN; d += nw) {
        int j0 = offs[d], j1 = offs[d + 1];
        float ax = 0.f, ay = 0.f;
        for (int j = j0; j < j1; ++j) {
            int2 r = eRec[j];
            float w = __int_as_float(r.y);
            u32 u = hwb[(size_t)r.x * 64 + lane];
            ax = fmaf(w, __uint_as_float(u << 16), ax);
            ay = fmaf(w, __uint_as_float(u & 0xffff0000u), ay);
        }
        float dd = dinv[d];
        ax *= dd; ay *= dd;
        agg2[(size_t)d * 64 + lane] = make_float2(ax, ay);
        sx0 += ax; sx1 += ay;
        sq0 += ax * ax; sq1 += ay * ay;
    }

    __shared__ float ls[512], lq[512];
    ls[wav * 128 + lane * 2]     = sx0;
    ls[wav * 128 + lane * 2 + 1] = sx1;
    lq[wav * 128 + lane * 2]     = sq0;
    lq[wav * 128 + lane * 2 + 1] = sq1;
    __syncthreads();
    if (tid < 128) {
        float s = ls[tid] + ls[tid + 128] + ls[tid + 256] + ls[tid + 384];
        float q = lq[tid] + lq[tid + 128] + lq[tid + 256] + lq[tid + 384];
        atomAddG(&sSum[tid], s);
        atomAddG(&sSq[tid], q);
    }
}

// ---------------- residual update ----------------
__global__ __launch_bounds__(256) void k_update(float* __restrict__ h, const float* __restrict__ agg,
                                                const float* __restrict__ scl, const float* __restrict__ shf) {
    int idx = (blockIdx.x * 256 + threadIdx.x) * 4;
    int c = idx & 127;
    float4 a = *(const float4*)(agg + idx);
    float4 hv = *(const float4*)(h + idx);
    float4 sv = *(const float4*)(scl + c);
    float4 fv = *(const float4*)(shf + c);
    hv.x += fmaxf(0.f, a.x * sv.x + fv.x);
    hv.y += fmaxf(0.f, a.y * sv.y + fv.y);
    hv.z += fmaxf(0.f, a.z * sv.z + fv.z);
    hv.w += fmaxf(0.f, a.w * sv.w + fv.w);
    *(float4*)(h + idx) = hv;
}

// ---------------- pooling ----------------
__global__ __launch_bounds__(128) void k_pool(const float* __restrict__ h, const int* __restrict__ batch,
                                              float* __restrict__ hg) {
    int c = threadIdx.x;
    int r0 = blockIdx.x * 256;
    int rend = min(r0 + 256, NN);
    float acc = 0.f;
    int cur = batch[r0];
    for (int r = r0; r < rend; ++r) {
        int b = batch[r];
        if (b != cur) { atomAddG(&hg[cur * DD + c], acc); acc = 0.f; cur = b; }
        acc += h[(size_t)r * DD + c];
    }
    atomAddG(&hg[cur * DD + c], acc);
}

// ---------------- readout MLP ----------------
__global__ __launch_bounds__(128) void k_readout(
    const float* __restrict__ hg,
    const float* __restrict__ W1, const float* __restrict__ b1,
    const float* __restrict__ W2, const float* __restrict__ b2,
    const float* __restrict__ W3, const float* __restrict__ b3,
    float* __restrict__ out) {
    __shared__ float a0[128], a1[64], a2[32];
    int g = blockIdx.x, t = threadIdx.x;
    a0[t] = hg[g * DD + t];
    __syncthreads();
    if (t < 64) {
        float s = b1[t];
        for (int k = 0; k < 128; ++k) s += a0[k] * W1[k * 64 + t];
        a1[t] = fmaxf(s, 0.f);
    }
    __syncthreads();
    if (t < 32) {
        float s = b2[t];
        for (int k = 0; k < 64; ++k) s += a1[k] * W2[k * 32 + t];
        a2[t] = fmaxf(s, 0.f);
    }
    __syncthreads();
    if (t == 0) {
        float s = b3[0];
        for (int k = 0; k < 32; ++k) s += a2[k] * W3[k];
        out[g] = s;
    }
}

extern "C" void kernel_launch(void* const* d_in, const int* in_sizes, int n_in,
                              void* d_out, int out_size, void* d_ws, size_t ws_size,
                              hipStream_t stream) {
    const float* x      = (const float*)d_in[0];
    const int*   ei     = (const int*)d_in[1];
    const int*   batch  = (const int*)d_in[2];
    const float* enc_W1 = (const float*)d_in[3];
    const float* enc_b1 = (const float*)d_in[4];
    const float* enc_g  = (const float*)d_in[5];
    const float* enc_be = (const float*)d_in[6];
    const float* enc_W2 = (const float*)d_in[7];
    const float* enc_b2 = (const float*)d_in[8];
    const float* conv_W = (const float*)d_in[9];
    // d_in[10] = conv_b: unused (BN absorbs additive pre-BN bias)
    const float* bn_g   = (const float*)d_in[11];
    const float* bn_b   = (const float*)d_in[12];
    const float* ro_W1  = (const float*)d_in[13];
    const float* ro_b1  = (const float*)d_in[14];
    const float* ro_W2  = (const float*)d_in[15];
    const float* ro_b2  = (const float*)d_in[16];
    const float* ro_W3  = (const float*)d_in[17];
    const float* ro_b3  = (const float*)d_in[18];

    const int* srcI = ei;
    const int* dstI = ei + NE;

    float* ws   = (float*)d_ws;
    float* h    = ws;                         // [NN*DD] f32
    float* agg  = ws + 12800000;              // [NN*DD] f32 (also encoder tmp)
    u16*   t1b  = (u16*)(ws + 25600000);      // [NN*DD] bf16
    float* dinv = ws + 32000000;              // [NN]
    float* sSum = ws + 32100000;              // 128
    float* sSq  = sSum + 128;
    float* scl  = sSum + 256;
    float* shf  = sSum + 384;
    float* hg   = ws + 32100512;              // [NG*DD]
    int*   offs = (int*)(ws + 32110000);      // [NN+1]
    int*   degI = (int*)(ws + 32220000);      // [NN] (histogram, then cursor)
    int*   bsum = (int*)(ws + 32320000);      // [512]
    int2*  eRec = (int2*)(ws + 32330000);     // [NE] {src, dinv_src bits}

    // ---- CSR build ----
    hipMemsetAsync(degI, 0, NN * sizeof(int), stream);
    k_degI<<<2500, 256, 0, stream>>>(dstI, degI);
    k_dinv<<<391, 256, 0, stream>>>(degI, dinv);
    k_scan1<<<391, 256, 0, stream>>>(degI, offs, bsum);
    k_scan2<<<1, 512, 0, stream>>>(bsum, 391);
    k_scan3<<<391, 256, 0, stream>>>(offs, bsum);
    hipMemsetAsync(degI, 0, NN * sizeof(int), stream);   // reuse as cursor
    k_place<<<2500, 256, 0, stream>>>(srcI, dstI, offs, degI, dinv, eRec);

    // ---- encoder: Linear -> BN -> ReLU -> Linear ----
    hipMemsetAsync(sSum, 0, 256 * sizeof(float), stream);
    k_gemm<1, false><<<3125, 256, 0, stream>>>(x, enc_W1, enc_b1, agg, nullptr, nullptr, sSum, sSq);
    k_bnfinal<<<1, 128, 0, stream>>>(sSum, sSq, enc_g, enc_be, scl, shf);
    k_gemm<2, false><<<3125, 256, 0, stream>>>(agg, enc_W2, enc_b2, h, scl, shf, nullptr, nullptr);

    // ---- GCN layers ----
    for (int l = 0; l < NL; ++l) {
        k_gemm<0, true><<<3125, 256, 0, stream>>>(h, conv_W + (size_t)l * DD * DD, nullptr, t1b,
                                                  nullptr, nullptr, nullptr, nullptr);
        hipMemsetAsync(sSum, 0, 256 * sizeof(float), stream);
        k_agg<<<2048, 256, 0, stream>>>((const u32*)t1b, eRec, offs, dinv, agg, sSum, sSq);
        k_bnfinal<<<1, 128, 0, stream>>>(sSum, sSq, bn_g + l * DD, bn_b + l * DD, scl, shf);
        k_update<<<12500, 256, 0, stream>>>(h, agg, scl, shf);
    }

    // ---- pooling + readout ----
    hipMemsetAsync(hg, 0, NG * DD * sizeof(float), stream);
    k_pool<<<391, 128, 0, stream>>>(h, batch, hg);
    k_readout<<<NG, 128, 0, stream>>>(hg, ro_W1, ro_b1, ro_W2, ro_b2, ro_W3, ro_b3, (float*)d_out);
}

// Round 3
// 737.618 us; speedup vs baseline: 5.4066x; 1.3070x over previous
//
#include <hip/hip_runtime.h>
#include <hip/hip_bf16.h>

#define NN 100000
#define NE 640000
#define DD 128
#define NG 64
#define NL 3
#define BN_EPS 1e-5f

typedef unsigned short u16;
typedef unsigned int u32;
typedef __attribute__((ext_vector_type(8))) short short8;
typedef __attribute__((ext_vector_type(4))) float f32x4;

__device__ __forceinline__ void atomAddG(float* p, float v) { unsafeAtomicAdd(p, v); }

__device__ __forceinline__ float bf_lo(u32 u) { return __uint_as_float(u << 16); }
__device__ __forceinline__ float bf_hi(u32 u) { return __uint_as_float(u & 0xffff0000u); }
__device__ __forceinline__ u32 pk(float a, float b) {
    __hip_bfloat16 x = __float2bfloat16(a), y = __float2bfloat16(b);
    return (u32)(*(u16*)&x) | ((u32)(*(u16*)&y) << 16);
}

// ---------------- CSR build ----------------
__global__ void k_degI(const int* __restrict__ dst, int* __restrict__ degI) {
    int e = blockIdx.x * 256 + threadIdx.x;
    if (e < NE) atomicAdd(&degI[dst[e]], 1);
}

__global__ void k_dinv(const int* __restrict__ degI, float* __restrict__ dinv) {
    int i = blockIdx.x * 256 + threadIdx.x;
    if (i < NN) { int d = degI[i]; dinv[i] = d > 0 ? rsqrtf((float)d) : 0.f; }
}

__global__ void k_scan1(const int* __restrict__ degI, int* __restrict__ offs, int* __restrict__ bsum) {
    __shared__ int ls[256];
    int t = threadIdx.x;
    int i = blockIdx.x * 256 + t;
    int v = (i < NN) ? degI[i] : 0;
    ls[t] = v;
    __syncthreads();
    for (int off = 1; off < 256; off <<= 1) {
        int u = (t >= off) ? ls[t - off] : 0;
        __syncthreads();
        ls[t] += u;
        __syncthreads();
    }
    if (i < NN) offs[i] = ls[t] - v;
    if (t == 255) bsum[blockIdx.x] = ls[255];
}

__global__ void k_scan2(int* __restrict__ bsum, int nb) {
    __shared__ int ls[512];
    int t = threadIdx.x;
    int v = (t < nb) ? bsum[t] : 0;
    ls[t] = v;
    __syncthreads();
    for (int off = 1; off < 512; off <<= 1) {
        int u = (t >= off) ? ls[t - off] : 0;
        __syncthreads();
        ls[t] += u;
        __syncthreads();
    }
    if (t < nb) bsum[t] = ls[t] - v;
}

__global__ void k_scan3(int* __restrict__ offs, const int* __restrict__ bsum) {
    int i = blockIdx.x * 256 + threadIdx.x;
    if (i < NN) offs[i] += bsum[blockIdx.x];
    if (i == 0) offs[NN] = NE;
}

__global__ void k_place(const int* __restrict__ src, const int* __restrict__ dst,
                        const int* __restrict__ offs, int* __restrict__ cur,
                        const float* __restrict__ dinv, int2* __restrict__ eRec) {
    int e = blockIdx.x * 256 + threadIdx.x;
    if (e < NE) {
        int d = dst[e], s = src[e];
        int pos = offs[d] + atomicAdd(&cur[d], 1);
        eRec[pos] = make_int2(s, __float_as_int(dinv[s]));
    }
}

// ---------------- prep: f32 -> bf16 conversions ----------------
__global__ void k_prepX(const float* __restrict__ x, u32* __restrict__ xb) {
    int i = blockIdx.x * 256 + threadIdx.x;       // handles 8 elements
    const float4* xp = (const float4*)(x + (size_t)i * 8);
    float4 a = xp[0], b = xp[1];
    uint4 o;
    o.x = pk(a.x, a.y); o.y = pk(a.z, a.w);
    o.z = pk(b.x, b.y); o.w = pk(b.z, b.w);
    *(uint4*)(xb + (size_t)i * 4) = o;
}

// W [k][n] f32 -> Wt [n][k] bf16 ; matrices: 0=enc_W1 1=enc_W2 2..4=conv_W
__global__ void k_prepW(const float* __restrict__ W1, const float* __restrict__ W2,
                        const float* __restrict__ CW, u16* __restrict__ wtb) {
    int m = blockIdx.x >> 3;
    const float* src = (m == 0) ? W1 : (m == 1) ? W2 : CW + (size_t)(m - 2) * 16384;
    u16* dst = wtb + (size_t)m * 16384;
    int base = (blockIdx.x & 7) * 2048 + threadIdx.x;
#pragma unroll
    for (int i = 0; i < 8; ++i) {
        int idx = base + i * 256;
        int k = idx >> 7, n = idx & 127;
        __hip_bfloat16 b = __float2bfloat16(src[idx]);
        dst[n * 128 + k] = *(u16*)&b;
    }
}

// ---------------- MFMA GEMM [NN,128] @ Wt[128][128] ----------------
// MODE 0: conv     (out bf16)
// MODE 1: encoder1 (out bf16, fused BN column stats; bias dead through BN)
// MODE 2: encoder2 (+bias, out bf16 AND f32)
template <int MODE>
__global__ __launch_bounds__(256) void k_mm(
    const u16* __restrict__ A, const u16* __restrict__ Wt,
    const float* __restrict__ bias,
    u16* __restrict__ Cb, float* __restrict__ Cf,
    float* __restrict__ sSum, float* __restrict__ sSq)
{
    __shared__ float lC[64 * 128];
    int tid = threadIdx.x;
    int l = tid & 63, w = tid >> 6;
    int lr = l & 15, lg = l >> 4;
    int wcol = (w & 1) * 64, wrow = (w >> 1) * 32;

    // B fragments: whole 64-col slice of Wt held in registers (L2-resident source)
    short8 Bf[4][4];
#pragma unroll
    for (int ct = 0; ct < 4; ++ct)
#pragma unroll
        for (int ks = 0; ks < 4; ++ks)
            Bf[ct][ks] = *(const short8*)(Wt + (size_t)(wcol + ct * 16 + lr) * 128 + ks * 32 + lg * 8);

    f32x4 acc[2][4];
#pragma unroll
    for (int rg = 0; rg < 2; ++rg)
#pragma unroll
        for (int ct = 0; ct < 4; ++ct)
            acc[rg][ct] = (f32x4){0.f, 0.f, 0.f, 0.f};

    int rbase = blockIdx.x * 64 + wrow;
#pragma unroll
    for (int rg = 0; rg < 2; ++rg) {
        int row = rbase + rg * 16 + lr;
        row = min(row, NN - 1);
        const u16* ap = A + (size_t)row * 128 + lg * 8;
        short8 Af[4];
#pragma unroll
        for (int ks = 0; ks < 4; ++ks) Af[ks] = *(const short8*)(ap + ks * 32);
#pragma unroll
        for (int ks = 0; ks < 4; ++ks)
#pragma unroll
            for (int ct = 0; ct < 4; ++ct)
                acc[rg][ct] = __builtin_amdgcn_mfma_f32_16x16x32_bf16(Af[ks], Bf[ct][ks], acc[rg][ct], 0, 0, 0);
    }

    if (MODE == 2) {
#pragma unroll
        for (int ct = 0; ct < 4; ++ct) {
            float bc = bias[wcol + ct * 16 + lr];
#pragma unroll
            for (int rg = 0; rg < 2; ++rg)
#pragma unroll
                for (int j = 0; j < 4; ++j) acc[rg][ct][j] += bc;
        }
    }

    // C/D layout: col = lane&15, row = (lane>>4)*4 + j  -> stage through LDS
#pragma unroll
    for (int rg = 0; rg < 2; ++rg)
#pragma unroll
        for (int ct = 0; ct < 4; ++ct)
#pragma unroll
            for (int j = 0; j < 4; ++j)
                lC[(wrow + rg * 16 + lg * 4 + j) * 128 + wcol + ct * 16 + lr] = acc[rg][ct][j];
    __syncthreads();

    float cs[4] = {0.f, 0.f, 0.f, 0.f}, cq[4] = {0.f, 0.f, 0.f, 0.f};
#pragma unroll
    for (int i = 0; i < 8; ++i) {
        int eidx = i * 1024 + tid * 4;
        int lrow = eidx >> 7;
        int col = eidx & 127;
        int grow = blockIdx.x * 64 + lrow;
        if (grow < NN) {
            float4 v = *(float4*)(lC + eidx);
            uint2 o = make_uint2(pk(v.x, v.y), pk(v.z, v.w));
            *(uint2*)(Cb + (size_t)grow * 128 + col) = o;
            if (MODE == 2) *(float4*)(Cf + (size_t)grow * 128 + col) = v;
            if (MODE == 1) {
                cs[0] += v.x; cs[1] += v.y; cs[2] += v.z; cs[3] += v.w;
                cq[0] += v.x * v.x; cq[1] += v.y * v.y; cq[2] += v.z * v.z; cq[3] += v.w * v.w;
            }
        }
    }

    if (MODE == 1) {
        __syncthreads();
        int g = tid >> 5, c0 = (tid & 31) * 4;
#pragma unroll
        for (int cc = 0; cc < 4; ++cc) {
            lC[g * 128 + c0 + cc] = cs[cc];
            lC[1024 + g * 128 + c0 + cc] = cq[cc];
        }
        __syncthreads();
        if (tid < 128) {
            float s = 0.f, q = 0.f;
#pragma unroll
            for (int g2 = 0; g2 < 8; ++g2) { s += lC[g2 * 128 + tid]; q += lC[1024 + g2 * 128 + tid]; }
            atomAddG(&sSum[tid], s);
            atomAddG(&sSq[tid], q);
        }
    }
}

// ---------------- BN finalize ----------------
__global__ void k_bnfinal(const float* __restrict__ sSum, const float* __restrict__ sSq,
                          const float* __restrict__ g, const float* __restrict__ be,
                          float* __restrict__ scl, float* __restrict__ shf) {
    int c = threadIdx.x;
    float m = sSum[c] * (1.0f / NN);
    float v = sSq[c] * (1.0f / NN) - m * m;
    float s = g[c] * rsqrtf(v + BN_EPS);
    scl[c] = s;
    shf[c] = be[c] - m * s;
}

// ---------------- in-place BN+ReLU on bf16 buffer ----------------
__global__ void k_bnrelu(u32* __restrict__ tb, const float* __restrict__ scl, const float* __restrict__ shf) {
    int i = blockIdx.x * 256 + threadIdx.x;   // 8 elements (4 u32)
    int c0 = (i * 8) & 127;
    uint4 u = *(uint4*)(tb + (size_t)i * 4);
    float4 s0 = *(const float4*)(scl + c0), s1 = *(const float4*)(scl + c0 + 4);
    float4 f0 = *(const float4*)(shf + c0), f1 = *(const float4*)(shf + c0 + 4);
    uint4 o;
    o.x = pk(fmaxf(0.f, bf_lo(u.x) * s0.x + f0.x), fmaxf(0.f, bf_hi(u.x) * s0.y + f0.y));
    o.y = pk(fmaxf(0.f, bf_lo(u.y) * s0.z + f0.z), fmaxf(0.f, bf_hi(u.y) * s0.w + f0.w));
    o.z = pk(fmaxf(0.f, bf_lo(u.z) * s1.x + f1.x), fmaxf(0.f, bf_hi(u.z) * s1.y + f1.y));
    o.w = pk(fmaxf(0.f, bf_lo(u.w) * s1.z + f1.z), fmaxf(0.f, bf_hi(u.w) * s1.w + f1.w));
    *(uint4*)(tb + (size_t)i * 4) = o;
}

// ---------------- CSR pull aggregation (bf16 in, bf16 out, f32 stats) ----------------
__global__ __launch_bounds__(256) void k_agg(
    const u32* __restrict__ hwb, const int2* __restrict__ eRec, const int* __restrict__ offs,
    const float* __restrict__ dinv,
    u32* __restrict__ aggb, float* __restrict__ sSum, float* __restrict__ sSq)
{
    int tid = threadIdx.x;
    int lane = tid & 63;
    int wav = tid >> 6;
    int gw = blockIdx.x * 4 + wav;
    int nw = gridDim.x * 4;
    float sx0 = 0.f, sx1 = 0.f, sq0 = 0.f, sq1 = 0.f;

    for (int d = gw; d < NN; d += nw) {
        int j0 = offs[d], j1 = offs[d + 1];
        float ax = 0.f, ay = 0.f;
        for (int j = j0; j < j1; ++j) {
            int2 r = eRec[j];
            float wgt = __int_as_float(r.y);
            u32 u = hwb[(size_t)r.x * 64 + lane];
            ax = fmaf(wgt, bf_lo(u), ax);
            ay = fmaf(wgt, bf_hi(u), ay);
        }
        float dd = dinv[d];
        ax *= dd; ay *= dd;
        aggb[(size_t)d * 64 + lane] = pk(ax, ay);
        sx0 += ax; sx1 += ay;
        sq0 += ax * ax; sq1 += ay * ay;
    }

    __shared__ float ls[512], lq[512];
    ls[wav * 128 + lane * 2] = sx0;
    ls[wav * 128 + lane * 2 + 1] = sx1;
    lq[wav * 128 + lane * 2] = sq0;
    lq[wav * 128 + lane * 2 + 1] = sq1;
    __syncthreads();
    if (tid < 128) {
        float s = ls[tid] + ls[tid + 128] + ls[tid + 256] + ls[tid + 384];
        float q = lq[tid] + lq[tid + 128] + lq[tid + 256] + lq[tid + 384];
        atomAddG(&sSum[tid], s);
        atomAddG(&sSq[tid], q);
    }
}

// ---------------- residual update: h += relu(agg*s+f); emit bf16 mirror ----------------
__global__ __launch_bounds__(256) void k_update(
    float* __restrict__ h, const u32* __restrict__ aggb,
    const float* __restrict__ scl, const float* __restrict__ shf,
    u32* __restrict__ hb)
{
    int i = blockIdx.x * 256 + threadIdx.x;   // 4 cols = 2 u32
    int c0 = (i * 4) & 127;
    uint2 a = *(const uint2*)(aggb + (size_t)i * 2);
    float4 hv = *(float4*)(h + (size_t)i * 4);
    float4 sv = *(const float4*)(scl + c0);
    float4 fv = *(const float4*)(shf + c0);
    hv.x += fmaxf(0.f, bf_lo(a.x) * sv.x + fv.x);
    hv.y += fmaxf(0.f, bf_hi(a.x) * sv.y + fv.y);
    hv.z += fmaxf(0.f, bf_lo(a.y) * sv.z + fv.z);
    hv.w += fmaxf(0.f, bf_hi(a.y) * sv.w + fv.w);
    *(float4*)(h + (size_t)i * 4) = hv;
    *(uint2*)(hb + (size_t)i * 2) = make_uint2(pk(hv.x, hv.y), pk(hv.z, hv.w));
}

// ---------------- pooling ----------------
__global__ __launch_bounds__(128) void k_pool(const float* __restrict__ h, const int* __restrict__ batch,
                                              float* __restrict__ hg) {
    int c = threadIdx.x;
    int r0 = blockIdx.x * 256;
    int rend = min(r0 + 256, NN);
    float acc = 0.f;
    int cur = batch[r0];
    for (int r = r0; r < rend; ++r) {
        int b = batch[r];
        if (b != cur) { atomAddG(&hg[cur * DD + c], acc); acc = 0.f; cur = b; }
        acc += h[(size_t)r * DD + c];
    }
    atomAddG(&hg[cur * DD + c], acc);
}

// ---------------- readout MLP ----------------
__global__ __launch_bounds__(128) void k_readout(
    const float* __restrict__ hg,
    const float* __restrict__ W1, const float* __restrict__ b1,
    const float* __restrict__ W2, const float* __restrict__ b2,
    const float* __restrict__ W3, const float* __restrict__ b3,
    float* __restrict__ out) {
    __shared__ float a0[128], a1[64], a2[32];
    int g = blockIdx.x, t = threadIdx.x;
    a0[t] = hg[g * DD + t];
    __syncthreads();
    if (t < 64) {
        float s = b1[t];
        for (int k = 0; k < 128; ++k) s += a0[k] * W1[k * 64 + t];
        a1[t] = fmaxf(s, 0.f);
    }
    __syncthreads();
    if (t < 32) {
        float s = b2[t];
        for (int k = 0; k < 64; ++k) s += a1[k] * W2[k * 32 + t];
        a2[t] = fmaxf(s, 0.f);
    }
    __syncthreads();
    if (t == 0) {
        float s = b3[0];
        for (int k = 0; k < 32; ++k) s += a2[k] * W3[k];
        out[g] = s;
    }
}

extern "C" void kernel_launch(void* const* d_in, const int* in_sizes, int n_in,
                              void* d_out, int out_size, void* d_ws, size_t ws_size,
                              hipStream_t stream) {
    const float* x      = (const float*)d_in[0];
    const int*   ei     = (const int*)d_in[1];
    const int*   batch  = (const int*)d_in[2];
    const float* enc_g  = (const float*)d_in[5];
    const float* enc_be = (const float*)d_in[6];
    const float* enc_W1 = (const float*)d_in[3];
    const float* enc_W2 = (const float*)d_in[7];
    const float* enc_b2 = (const float*)d_in[8];
    const float* conv_W = (const float*)d_in[9];
    // d_in[4]=enc_b1, d_in[10]=conv_b: dead (additive pre-BN bias cancels in BN)
    const float* bn_g   = (const float*)d_in[11];
    const float* bn_b   = (const float*)d_in[12];
    const float* ro_W1  = (const float*)d_in[13];
    const float* ro_b1  = (const float*)d_in[14];
    const float* ro_W2  = (const float*)d_in[15];
    const float* ro_b2  = (const float*)d_in[16];
    const float* ro_W3  = (const float*)d_in[17];
    const float* ro_b3  = (const float*)d_in[18];

    const int* srcI = ei;
    const int* dstI = ei + NE;

    float* ws   = (float*)d_ws;
    float* h    = ws;                          // [NN*DD] f32
    u32*   aggb = (u32*)(ws + 12800000);       // [NN*64] u32 (bf16x2) — aliases encoder tb
    u32*   hb   = (u32*)(ws + 19200000);       // [NN*64] u32
    u32*   t1b  = (u32*)(ws + 25600000);       // [NN*64] u32 — aliases xb
    u16*   wtb  = (u16*)(ws + 32000000);       // 5*16384 bf16
    float* dinv = ws + 32050000;               // [NN]
    float* sSum = ws + 32150000;               // 128
    float* sSq  = sSum + 128;
    float* scl  = sSum + 256;
    float* shf  = sSum + 384;
    float* hg   = ws + 32150512;               // [NG*DD]
    int*   offs = (int*)(ws + 32160000);       // [NN+1]
    int*   degI = (int*)(ws + 32270000);       // [NN]
    int*   bsum = (int*)(ws + 32370000);       // [512]
    int2*  eRec = (int2*)(ws + 32380000);      // [NE]

    u16* tb16 = (u16*)aggb;   // encoder tmp (bf16) aliases aggb
    u16* xb16 = (u16*)t1b;    // x bf16 aliases t1b

    // ---- prep ----
    k_prepW<<<40, 256, 0, stream>>>(enc_W1, enc_W2, conv_W, wtb);
    k_prepX<<<6250, 256, 0, stream>>>(x, (u32*)xb16);

    // ---- CSR build ----
    hipMemsetAsync(degI, 0, NN * sizeof(int), stream);
    k_degI<<<2500, 256, 0, stream>>>(dstI, degI);
    k_dinv<<<391, 256, 0, stream>>>(degI, dinv);
    k_scan1<<<391, 256, 0, stream>>>(degI, offs, bsum);
    k_scan2<<<1, 512, 0, stream>>>(bsum, 391);
    k_scan3<<<391, 256, 0, stream>>>(offs, bsum);
    hipMemsetAsync(degI, 0, NN * sizeof(int), stream);
    k_place<<<2500, 256, 0, stream>>>(srcI, dstI, offs, degI, dinv, eRec);

    // ---- encoder ----
    hipMemsetAsync(sSum, 0, 256 * sizeof(float), stream);
    k_mm<1><<<1563, 256, 0, stream>>>(xb16, wtb, nullptr, tb16, nullptr, sSum, sSq);
    k_bnfinal<<<1, 128, 0, stream>>>(sSum, sSq, enc_g, enc_be, scl, shf);
    k_bnrelu<<<6250, 256, 0, stream>>>((u32*)tb16, scl, shf);
    k_mm<2><<<1563, 256, 0, stream>>>(tb16, wtb + 16384, enc_b2, (u16*)hb, h, nullptr, nullptr);

    // ---- GCN layers ----
    for (int l = 0; l < NL; ++l) {
        k_mm<0><<<1563, 256, 0, stream>>>((const u16*)hb, wtb + (size_t)(2 + l) * 16384, nullptr,
                                          (u16*)t1b, nullptr, nullptr, nullptr);
        hipMemsetAsync(sSum, 0, 256 * sizeof(float), stream);
        k_agg<<<2048, 256, 0, stream>>>(t1b, eRec, offs, dinv, aggb, sSum, sSq);
        k_bnfinal<<<1, 128, 0, stream>>>(sSum, sSq, bn_g + l * DD, bn_b + l * DD, scl, shf);
        k_update<<<12500, 256, 0, stream>>>(h, aggb, scl, shf, hb);
    }

    // ---- pooling + readout ----
    hipMemsetAsync(hg, 0, NG * DD * sizeof(float), stream);
    k_pool<<<391, 128, 0, stream>>>(h, batch, hg);
    k_readout<<<NG, 128, 0, stream>>>(hg, ro_W1, ro_b1, ro_W2, ro_b2, ro_W3, ro_b3, (float*)d_out);
}

// Round 4
// 735.033 us; speedup vs baseline: 5.4256x; 1.0035x over previous
//
#include <hip/hip_runtime.h>
#include <hip/hip_bf16.h>

#define NN 100000
#define NE 640000
#define DD 128
#define NG 64
#define NL 3
#define BN_EPS 1e-5f

typedef unsigned short u16;
typedef unsigned int u32;
typedef __attribute__((ext_vector_type(8))) short short8;
typedef __attribute__((ext_vector_type(4))) float f32x4;

__device__ __forceinline__ void atomAddG(float* p, float v) { unsafeAtomicAdd(p, v); }

__device__ __forceinline__ float bf_lo(u32 u) { return __uint_as_float(u << 16); }
__device__ __forceinline__ float bf_hi(u32 u) { return __uint_as_float(u & 0xffff0000u); }
__device__ __forceinline__ u32 pk(float a, float b) {
    __hip_bfloat16 x = __float2bfloat16(a), y = __float2bfloat16(b);
    return (u32)(*(u16*)&x) | ((u32)(*(u16*)&y) << 16);
}

// ---------------- CSR build ----------------
__global__ void k_degI(const int* __restrict__ dst, int* __restrict__ degI) {
    int e = blockIdx.x * 256 + threadIdx.x;
    if (e < NE) atomicAdd(&degI[dst[e]], 1);
}

__global__ void k_dinv(const int* __restrict__ degI, float* __restrict__ dinv) {
    int i = blockIdx.x * 256 + threadIdx.x;
    if (i < NN) { int d = degI[i]; dinv[i] = d > 0 ? rsqrtf((float)d) : 0.f; }
}

__global__ void k_scan1(const int* __restrict__ degI, int* __restrict__ offs, int* __restrict__ bsum) {
    __shared__ int ls[256];
    int t = threadIdx.x;
    int i = blockIdx.x * 256 + t;
    int v = (i < NN) ? degI[i] : 0;
    ls[t] = v;
    __syncthreads();
    for (int off = 1; off < 256; off <<= 1) {
        int u = (t >= off) ? ls[t - off] : 0;
        __syncthreads();
        ls[t] += u;
        __syncthreads();
    }
    if (i < NN) offs[i] = ls[t] - v;
    if (t == 255) bsum[blockIdx.x] = ls[255];
}

__global__ void k_scan2(int* __restrict__ bsum, int nb) {
    __shared__ int ls[512];
    int t = threadIdx.x;
    int v = (t < nb) ? bsum[t] : 0;
    ls[t] = v;
    __syncthreads();
    for (int off = 1; off < 512; off <<= 1) {
        int u = (t >= off) ? ls[t - off] : 0;
        __syncthreads();
        ls[t] += u;
        __syncthreads();
    }
    if (t < nb) bsum[t] = ls[t] - v;
}

__global__ void k_scan3(int* __restrict__ offs, const int* __restrict__ bsum) {
    int i = blockIdx.x * 256 + threadIdx.x;
    if (i < NN) offs[i] += bsum[blockIdx.x];
    if (i == 0) offs[NN] = NE;
}

__global__ void k_place(const int* __restrict__ src, const int* __restrict__ dst,
                        const int* __restrict__ offs, int* __restrict__ cur,
                        const float* __restrict__ dinv, int2* __restrict__ eRec) {
    int e = blockIdx.x * 256 + threadIdx.x;
    if (e < NE) {
        int d = dst[e], s = src[e];
        int pos = offs[d] + atomicAdd(&cur[d], 1);
        eRec[pos] = make_int2(s, __float_as_int(dinv[s]));
    }
}

// ---------------- prep: f32 -> bf16 conversions ----------------
__global__ void k_prepX(const float* __restrict__ x, u32* __restrict__ xb) {
    int i = blockIdx.x * 256 + threadIdx.x;
    const float4* xp = (const float4*)(x + (size_t)i * 8);
    float4 a = xp[0], b = xp[1];
    uint4 o;
    o.x = pk(a.x, a.y); o.y = pk(a.z, a.w);
    o.z = pk(b.x, b.y); o.w = pk(b.z, b.w);
    *(uint4*)(xb + (size_t)i * 4) = o;
}

// W [k][n] f32 -> Wt [n][k] bf16 ; matrices: 0=enc_W1 1=enc_W2 2..4=conv_W
__global__ void k_prepW(const float* __restrict__ W1, const float* __restrict__ W2,
                        const float* __restrict__ CW, u16* __restrict__ wtb) {
    int m = blockIdx.x >> 3;
    const float* src = (m == 0) ? W1 : (m == 1) ? W2 : CW + (size_t)(m - 2) * 16384;
    u16* dst = wtb + (size_t)m * 16384;
    int base = (blockIdx.x & 7) * 2048 + threadIdx.x;
#pragma unroll
    for (int i = 0; i < 8; ++i) {
        int idx = base + i * 256;
        int k = idx >> 7, n = idx & 127;
        __hip_bfloat16 b = __float2bfloat16(src[idx]);
        dst[n * 128 + k] = *(u16*)&b;
    }
}

// ---------------- MFMA GEMM [NN,128] @ Wt[128][128] ----------------
// MODE 0: conv (out bf16); MODE 1: encoder1 (out bf16 + BN stats); MODE 2: encoder2 (+bias, bf16+f32)
template <int MODE>
__global__ __launch_bounds__(256) void k_mm(
    const u16* __restrict__ A, const u16* __restrict__ Wt,
    const float* __restrict__ bias,
    u16* __restrict__ Cb, float* __restrict__ Cf,
    float* __restrict__ sSum, float* __restrict__ sSq)
{
    __shared__ float lC[64 * 128];
    int tid = threadIdx.x;
    int l = tid & 63, w = tid >> 6;
    int lr = l & 15, lg = l >> 4;
    int wcol = (w & 1) * 64, wrow = (w >> 1) * 32;

    short8 Bf[4][4];
#pragma unroll
    for (int ct = 0; ct < 4; ++ct)
#pragma unroll
        for (int ks = 0; ks < 4; ++ks)
            Bf[ct][ks] = *(const short8*)(Wt + (size_t)(wcol + ct * 16 + lr) * 128 + ks * 32 + lg * 8);

    f32x4 acc[2][4];
#pragma unroll
    for (int rg = 0; rg < 2; ++rg)
#pragma unroll
        for (int ct = 0; ct < 4; ++ct)
            acc[rg][ct] = (f32x4){0.f, 0.f, 0.f, 0.f};

    int rbase = blockIdx.x * 64 + wrow;
#pragma unroll
    for (int rg = 0; rg < 2; ++rg) {
        int row = rbase + rg * 16 + lr;
        row = min(row, NN - 1);
        const u16* ap = A + (size_t)row * 128 + lg * 8;
        short8 Af[4];
#pragma unroll
        for (int ks = 0; ks < 4; ++ks) Af[ks] = *(const short8*)(ap + ks * 32);
#pragma unroll
        for (int ks = 0; ks < 4; ++ks)
#pragma unroll
            for (int ct = 0; ct < 4; ++ct)
                acc[rg][ct] = __builtin_amdgcn_mfma_f32_16x16x32_bf16(Af[ks], Bf[ct][ks], acc[rg][ct], 0, 0, 0);
    }

    if (MODE == 2) {
#pragma unroll
        for (int ct = 0; ct < 4; ++ct) {
            float bc = bias[wcol + ct * 16 + lr];
#pragma unroll
            for (int rg = 0; rg < 2; ++rg)
#pragma unroll
                for (int j = 0; j < 4; ++j) acc[rg][ct][j] += bc;
        }
    }

#pragma unroll
    for (int rg = 0; rg < 2; ++rg)
#pragma unroll
        for (int ct = 0; ct < 4; ++ct)
#pragma unroll
            for (int j = 0; j < 4; ++j)
                lC[(wrow + rg * 16 + lg * 4 + j) * 128 + wcol + ct * 16 + lr] = acc[rg][ct][j];
    __syncthreads();

    float cs[4] = {0.f, 0.f, 0.f, 0.f}, cq[4] = {0.f, 0.f, 0.f, 0.f};
#pragma unroll
    for (int i = 0; i < 8; ++i) {
        int eidx = i * 1024 + tid * 4;
        int lrow = eidx >> 7;
        int col = eidx & 127;
        int grow = blockIdx.x * 64 + lrow;
        if (grow < NN) {
            float4 v = *(float4*)(lC + eidx);
            uint2 o = make_uint2(pk(v.x, v.y), pk(v.z, v.w));
            *(uint2*)(Cb + (size_t)grow * 128 + col) = o;
            if (MODE == 2) *(float4*)(Cf + (size_t)grow * 128 + col) = v;
            if (MODE == 1) {
                cs[0] += v.x; cs[1] += v.y; cs[2] += v.z; cs[3] += v.w;
                cq[0] += v.x * v.x; cq[1] += v.y * v.y; cq[2] += v.z * v.z; cq[3] += v.w * v.w;
            }
        }
    }

    if (MODE == 1) {
        __syncthreads();
        int g = tid >> 5, c0 = (tid & 31) * 4;
#pragma unroll
        for (int cc = 0; cc < 4; ++cc) {
            lC[g * 128 + c0 + cc] = cs[cc];
            lC[1024 + g * 128 + c0 + cc] = cq[cc];
        }
        __syncthreads();
        if (tid < 128) {
            float s = 0.f, q = 0.f;
#pragma unroll
            for (int g2 = 0; g2 < 8; ++g2) { s += lC[g2 * 128 + tid]; q += lC[1024 + g2 * 128 + tid]; }
            atomAddG(&sSum[tid], s);
            atomAddG(&sSq[tid], q);
        }
    }
}

// ---------------- BN finalize ----------------
__global__ void k_bnfinal(const float* __restrict__ sSum, const float* __restrict__ sSq,
                          const float* __restrict__ g, const float* __restrict__ be,
                          float* __restrict__ scl, float* __restrict__ shf) {
    int c = threadIdx.x;
    float m = sSum[c] * (1.0f / NN);
    float v = sSq[c] * (1.0f / NN) - m * m;
    float s = g[c] * rsqrtf(v + BN_EPS);
    scl[c] = s;
    shf[c] = be[c] - m * s;
}

// ---------------- in-place BN+ReLU on bf16 buffer ----------------
__global__ void k_bnrelu(u32* __restrict__ tb, const float* __restrict__ scl, const float* __restrict__ shf) {
    int i = blockIdx.x * 256 + threadIdx.x;
    int c0 = (i * 8) & 127;
    uint4 u = *(uint4*)(tb + (size_t)i * 4);
    float4 s0 = *(const float4*)(scl + c0), s1 = *(const float4*)(scl + c0 + 4);
    float4 f0 = *(const float4*)(shf + c0), f1 = *(const float4*)(shf + c0 + 4);
    uint4 o;
    o.x = pk(fmaxf(0.f, bf_lo(u.x) * s0.x + f0.x), fmaxf(0.f, bf_hi(u.x) * s0.y + f0.y));
    o.y = pk(fmaxf(0.f, bf_lo(u.y) * s0.z + f0.z), fmaxf(0.f, bf_hi(u.y) * s0.w + f0.w));
    o.z = pk(fmaxf(0.f, bf_lo(u.z) * s1.x + f1.x), fmaxf(0.f, bf_hi(u.z) * s1.y + f1.y));
    o.w = pk(fmaxf(0.f, bf_lo(u.w) * s1.z + f1.z), fmaxf(0.f, bf_hi(u.w) * s1.w + f1.w));
    *(uint4*)(tb + (size_t)i * 4) = o;
}

// ---------------- CSR pull aggregation: 4 dsts interleaved per wave ----------------
// NN % 4 == 0, so each wave's 4 consecutive dsts need no individual bounds checks.
__global__ __launch_bounds__(256) void k_agg(
    const u32* __restrict__ hwb, const int2* __restrict__ eRec, const int* __restrict__ offs,
    const float* __restrict__ dinv,
    u32* __restrict__ aggb, float* __restrict__ sSum, float* __restrict__ sSq)
{
    int tid = threadIdx.x;
    int lane = tid & 63;
    int wav = tid >> 6;
    int gw = blockIdx.x * 4 + wav;
    int nw = gridDim.x * 4;
    float sx0 = 0.f, sx1 = 0.f, sq0 = 0.f, sq1 = 0.f;

    for (int d0 = gw * 4; d0 < NN; d0 += nw * 4) {
        int o0 = offs[d0], o1 = offs[d0 + 1], o2 = offs[d0 + 2], o3 = offs[d0 + 3], o4 = offs[d0 + 4];
        int jc[4] = {o0, o1, o2, o3};
        int je[4] = {o1, o2, o3, o4};
        float ax[4] = {0.f, 0.f, 0.f, 0.f}, ay[4] = {0.f, 0.f, 0.f, 0.f};
        int mx = max(max(je[0] - jc[0], je[1] - jc[1]), max(je[2] - jc[2], je[3] - jc[3]));
        for (int it = 0; it < mx; ++it) {
#pragma unroll
            for (int q = 0; q < 4; ++q) {
                if (jc[q] < je[q]) {
                    int2 r = eRec[jc[q]++];
                    float wgt = __int_as_float(r.y);
                    u32 u = hwb[(size_t)r.x * 64 + lane];
                    ax[q] = fmaf(wgt, bf_lo(u), ax[q]);
                    ay[q] = fmaf(wgt, bf_hi(u), ay[q]);
                }
            }
        }
#pragma unroll
        for (int q = 0; q < 4; ++q) {
            float dd = dinv[d0 + q];
            float vx = ax[q] * dd, vy = ay[q] * dd;
            aggb[(size_t)(d0 + q) * 64 + lane] = pk(vx, vy);
            sx0 += vx; sx1 += vy;
            sq0 += vx * vx; sq1 += vy * vy;
        }
    }

    __shared__ float ls[512], lq[512];
    ls[wav * 128 + lane * 2] = sx0;
    ls[wav * 128 + lane * 2 + 1] = sx1;
    lq[wav * 128 + lane * 2] = sq0;
    lq[wav * 128 + lane * 2 + 1] = sq1;
    __syncthreads();
    if (tid < 128) {
        float s = ls[tid] + ls[tid + 128] + ls[tid + 256] + ls[tid + 384];
        float q = lq[tid] + lq[tid + 128] + lq[tid + 256] + lq[tid + 384];
        atomAddG(&sSum[tid], s);
        atomAddG(&sSq[tid], q);
    }
}

// ---------------- residual update: h += relu(agg*s+f); emit bf16 mirror ----------------
__global__ __launch_bounds__(256) void k_update(
    float* __restrict__ h, const u32* __restrict__ aggb,
    const float* __restrict__ scl, const float* __restrict__ shf,
    u32* __restrict__ hb)
{
    int i = blockIdx.x * 256 + threadIdx.x;
    int c0 = (i * 4) & 127;
    uint2 a = *(const uint2*)(aggb + (size_t)i * 2);
    float4 hv = *(float4*)(h + (size_t)i * 4);
    float4 sv = *(const float4*)(scl + c0);
    float4 fv = *(const float4*)(shf + c0);
    hv.x += fmaxf(0.f, bf_lo(a.x) * sv.x + fv.x);
    hv.y += fmaxf(0.f, bf_hi(a.x) * sv.y + fv.y);
    hv.z += fmaxf(0.f, bf_lo(a.y) * sv.z + fv.z);
    hv.w += fmaxf(0.f, bf_hi(a.y) * sv.w + fv.w);
    *(float4*)(h + (size_t)i * 4) = hv;
    *(uint2*)(hb + (size_t)i * 2) = make_uint2(pk(hv.x, hv.y), pk(hv.z, hv.w));
}

// ---------------- pooling ----------------
__global__ __launch_bounds__(128) void k_pool(const float* __restrict__ h, const int* __restrict__ batch,
                                              float* __restrict__ hg) {
    int c = threadIdx.x;
    int r0 = blockIdx.x * 256;
    int rend = min(r0 + 256, NN);
    float acc = 0.f;
    int cur = batch[r0];
    for (int r = r0; r < rend; ++r) {
        int b = batch[r];
        if (b != cur) { atomAddG(&hg[cur * DD + c], acc); acc = 0.f; cur = b; }
        acc += h[(size_t)r * DD + c];
    }
    atomAddG(&hg[cur * DD + c], acc);
}

// ---------------- readout MLP ----------------
__global__ __launch_bounds__(128) void k_readout(
    const float* __restrict__ hg,
    const float* __restrict__ W1, const float* __restrict__ b1,
    const float* __restrict__ W2, const float* __restrict__ b2,
    const float* __restrict__ W3, const float* __restrict__ b3,
    float* __restrict__ out) {
    __shared__ float a0[128], a1[64], a2[32];
    int g = blockIdx.x, t = threadIdx.x;
    a0[t] = hg[g * DD + t];
    __syncthreads();
    if (t < 64) {
        float s = b1[t];
        for (int k = 0; k < 128; ++k) s += a0[k] * W1[k * 64 + t];
        a1[t] = fmaxf(s, 0.f);
    }
    __syncthreads();
    if (t < 32) {
        float s = b2[t];
        for (int k = 0; k < 64; ++k) s += a1[k] * W2[k * 32 + t];
        a2[t] = fmaxf(s, 0.f);
    }
    __syncthreads();
    if (t == 0) {
        float s = b3[0];
        for (int k = 0; k < 32; ++k) s += a2[k] * W3[k];
        out[g] = s;
    }
}

extern "C" void kernel_launch(void* const* d_in, const int* in_sizes, int n_in,
                              void* d_out, int out_size, void* d_ws, size_t ws_size,
                              hipStream_t stream) {
    const float* x      = (const float*)d_in[0];
    const int*   ei     = (const int*)d_in[1];
    const int*   batch  = (const int*)d_in[2];
    const float* enc_W1 = (const float*)d_in[3];
    const float* enc_g  = (const float*)d_in[5];
    const float* enc_be = (const float*)d_in[6];
    const float* enc_W2 = (const float*)d_in[7];
    const float* enc_b2 = (const float*)d_in[8];
    const float* conv_W = (const float*)d_in[9];
    // d_in[4]=enc_b1, d_in[10]=conv_b: dead (additive pre-BN bias cancels in BN)
    const float* bn_g   = (const float*)d_in[11];
    const float* bn_b   = (const float*)d_in[12];
    const float* ro_W1  = (const float*)d_in[13];
    const float* ro_b1  = (const float*)d_in[14];
    const float* ro_W2  = (const float*)d_in[15];
    const float* ro_b2  = (const float*)d_in[16];
    const float* ro_W3  = (const float*)d_in[17];
    const float* ro_b3  = (const float*)d_in[18];

    const int* srcI = ei;
    const int* dstI = ei + NE;

    float* ws   = (float*)d_ws;
    float* h    = ws;                          // [NN*DD] f32
    u32*   aggb = (u32*)(ws + 12800000);       // [NN*64] u32 (bf16x2) — aliases encoder tb
    u32*   hb   = (u32*)(ws + 19200000);       // [NN*64] u32
    u32*   t1b  = (u32*)(ws + 25600000);       // [NN*64] u32 — aliases xb
    u16*   wtb  = (u16*)(ws + 32000000);       // 5*16384 bf16
    float* dinv = ws + 32050000;               // [NN]
    float* sSum = ws + 32150000;               // 128
    float* sSq  = sSum + 128;
    float* scl  = sSum + 256;
    float* shf  = sSum + 384;
    float* hg   = ws + 32150512;               // [NG*DD]
    int*   offs = (int*)(ws + 32160000);       // [NN+1]
    int*   degI = (int*)(ws + 32270000);       // [NN]
    int*   bsum = (int*)(ws + 32370000);       // [512]
    int2*  eRec = (int2*)(ws + 32380000);      // [NE]

    u16* tb16 = (u16*)aggb;
    u16* xb16 = (u16*)t1b;

    // ---- prep ----
    k_prepW<<<40, 256, 0, stream>>>(enc_W1, enc_W2, conv_W, wtb);
    k_prepX<<<6250, 256, 0, stream>>>(x, (u32*)xb16);

    // ---- CSR build ----
    hipMemsetAsync(degI, 0, NN * sizeof(int), stream);
    k_degI<<<2500, 256, 0, stream>>>(dstI, degI);
    k_dinv<<<391, 256, 0, stream>>>(degI, dinv);
    k_scan1<<<391, 256, 0, stream>>>(degI, offs, bsum);
    k_scan2<<<1, 512, 0, stream>>>(bsum, 391);
    k_scan3<<<391, 256, 0, stream>>>(offs, bsum);
    hipMemsetAsync(degI, 0, NN * sizeof(int), stream);
    k_place<<<2500, 256, 0, stream>>>(srcI, dstI, offs, degI, dinv, eRec);

    // ---- encoder ----
    hipMemsetAsync(sSum, 0, 256 * sizeof(float), stream);
    k_mm<1><<<1563, 256, 0, stream>>>(xb16, wtb, nullptr, tb16, nullptr, sSum, sSq);
    k_bnfinal<<<1, 128, 0, stream>>>(sSum, sSq, enc_g, enc_be, scl, shf);
    k_bnrelu<<<6250, 256, 0, stream>>>((u32*)tb16, scl, shf);
    k_mm<2><<<1563, 256, 0, stream>>>(tb16, wtb + 16384, enc_b2, (u16*)hb, h, nullptr, nullptr);

    // ---- GCN layers ----
    for (int l = 0; l < NL; ++l) {
        k_mm<0><<<1563, 256, 0, stream>>>((const u16*)hb, wtb + (size_t)(2 + l) * 16384, nullptr,
                                          (u16*)t1b, nullptr, nullptr, nullptr);
        hipMemsetAsync(sSum, 0, 256 * sizeof(float), stream);
        k_agg<<<2048, 256, 0, stream>>>(t1b, eRec, offs, dinv, aggb, sSum, sSq);
        k_bnfinal<<<1, 128, 0, stream>>>(sSum, sSq, bn_g + l * DD, bn_b + l * DD, scl, shf);
        k_update<<<12500, 256, 0, stream>>>(h, aggb, scl, shf, hb);
    }

    // ---- pooling + readout ----
    hipMemsetAsync(hg, 0, NG * DD * sizeof(float), stream);
    k_pool<<<391, 128, 0, stream>>>(h, batch, hg);
    k_readout<<<NG, 128, 0, stream>>>(hg, ro_W1, ro_b1, ro_W2, ro_b2, ro_W3, ro_b3, (float*)d_out);
}

// Round 5
// 665.282 us; speedup vs baseline: 5.9944x; 1.1048x over previous
//
#include <hip/hip_runtime.h>
#include <hip/hip_bf16.h>

#define NN 100000
#define NE 640000
#define DD 128
#define NG 64
#define NL 3
#define BN_EPS 1e-5f

typedef unsigned short u16;
typedef unsigned int u32;
typedef __attribute__((ext_vector_type(8))) short short8;
typedef __attribute__((ext_vector_type(4))) float f32x4;

__device__ __forceinline__ void atomAddG(float* p, float v) { unsafeAtomicAdd(p, v); }

__device__ __forceinline__ float bf_lo(u32 u) { return __uint_as_float(u << 16); }
__device__ __forceinline__ float bf_hi(u32 u) { return __uint_as_float(u & 0xffff0000u); }
__device__ __forceinline__ u32 pk(float a, float b) {
    __hip_bfloat16 x = __float2bfloat16(a), y = __float2bfloat16(b);
    return (u32)(*(u16*)&x) | ((u32)(*(u16*)&y) << 16);
}

// ---------------- CSR build ----------------
__global__ void k_degI(const int* __restrict__ dst, int* __restrict__ degI) {
    int e = blockIdx.x * 256 + threadIdx.x;
    if (e < NE) atomicAdd(&degI[dst[e]], 1);
}

__global__ void k_dinv(const int* __restrict__ degI, float* __restrict__ dinv) {
    int i = blockIdx.x * 256 + threadIdx.x;
    if (i < NN) { int d = degI[i]; dinv[i] = d > 0 ? rsqrtf((float)d) : 0.f; }
}

__global__ void k_scan1(const int* __restrict__ degI, int* __restrict__ offs, int* __restrict__ bsum) {
    __shared__ int ls[256];
    int t = threadIdx.x;
    int i = blockIdx.x * 256 + t;
    int v = (i < NN) ? degI[i] : 0;
    ls[t] = v;
    __syncthreads();
    for (int off = 1; off < 256; off <<= 1) {
        int u = (t >= off) ? ls[t - off] : 0;
        __syncthreads();
        ls[t] += u;
        __syncthreads();
    }
    if (i < NN) offs[i] = ls[t] - v;
    if (t == 255) bsum[blockIdx.x] = ls[255];
}

__global__ void k_scan2(int* __restrict__ bsum, int nb) {
    __shared__ int ls[512];
    int t = threadIdx.x;
    int v = (t < nb) ? bsum[t] : 0;
    ls[t] = v;
    __syncthreads();
    for (int off = 1; off < 512; off <<= 1) {
        int u = (t >= off) ? ls[t - off] : 0;
        __syncthreads();
        ls[t] += u;
        __syncthreads();
    }
    if (t < nb) bsum[t] = ls[t] - v;
}

__global__ void k_scan3(int* __restrict__ offs, const int* __restrict__ bsum) {
    int i = blockIdx.x * 256 + threadIdx.x;
    if (i < NN) offs[i] += bsum[blockIdx.x];
    if (i == 0) offs[NN] = NE;
}

__global__ void k_place(const int* __restrict__ src, const int* __restrict__ dst,
                        const int* __restrict__ offs, int* __restrict__ cur,
                        const float* __restrict__ dinv, int2* __restrict__ eRec) {
    int e = blockIdx.x * 256 + threadIdx.x;
    if (e < NE) {
        int d = dst[e], s = src[e];
        int pos = offs[d] + atomicAdd(&cur[d], 1);
        eRec[pos] = make_int2(s, __float_as_int(dinv[s]));
    }
}

// ---------------- prep: f32 -> bf16 conversions ----------------
__global__ void k_prepX(const float* __restrict__ x, u32* __restrict__ xb) {
    int i = blockIdx.x * 256 + threadIdx.x;
    const float4* xp = (const float4*)(x + (size_t)i * 8);
    float4 a = xp[0], b = xp[1];
    uint4 o;
    o.x = pk(a.x, a.y); o.y = pk(a.z, a.w);
    o.z = pk(b.x, b.y); o.w = pk(b.z, b.w);
    *(uint4*)(xb + (size_t)i * 4) = o;
}

// W [k][n] f32 -> Wt [n][k] bf16 ; matrices: 0=enc_W1 1=enc_W2 2..4=conv_W
__global__ void k_prepW(const float* __restrict__ W1, const float* __restrict__ W2,
                        const float* __restrict__ CW, u16* __restrict__ wtb) {
    int m = blockIdx.x >> 3;
    const float* src = (m == 0) ? W1 : (m == 1) ? W2 : CW + (size_t)(m - 2) * 16384;
    u16* dst = wtb + (size_t)m * 16384;
    int base = (blockIdx.x & 7) * 2048 + threadIdx.x;
#pragma unroll
    for (int i = 0; i < 8; ++i) {
        int idx = base + i * 256;
        int k = idx >> 7, n = idx & 127;
        __hip_bfloat16 b = __float2bfloat16(src[idx]);
        dst[n * 128 + k] = *(u16*)&b;
    }
}

// ---------------- MFMA GEMM [NN,128] @ Wt[128][128] ----------------
// MODE 0: conv (out bf16); MODE 1: encoder1 (out bf16 + BN stats); MODE 2: encoder2 (+bias, bf16+f32)
template <int MODE>
__global__ __launch_bounds__(256) void k_mm(
    const u16* __restrict__ A, const u16* __restrict__ Wt,
    const float* __restrict__ bias,
    u16* __restrict__ Cb, float* __restrict__ Cf,
    float* __restrict__ sSum, float* __restrict__ sSq)
{
    __shared__ float lC[64 * 128];
    int tid = threadIdx.x;
    int l = tid & 63, w = tid >> 6;
    int lr = l & 15, lg = l >> 4;
    int wcol = (w & 1) * 64, wrow = (w >> 1) * 32;

    short8 Bf[4][4];
#pragma unroll
    for (int ct = 0; ct < 4; ++ct)
#pragma unroll
        for (int ks = 0; ks < 4; ++ks)
            Bf[ct][ks] = *(const short8*)(Wt + (size_t)(wcol + ct * 16 + lr) * 128 + ks * 32 + lg * 8);

    f32x4 acc[2][4];
#pragma unroll
    for (int rg = 0; rg < 2; ++rg)
#pragma unroll
        for (int ct = 0; ct < 4; ++ct)
            acc[rg][ct] = (f32x4){0.f, 0.f, 0.f, 0.f};

    int rbase = blockIdx.x * 64 + wrow;
#pragma unroll
    for (int rg = 0; rg < 2; ++rg) {
        int row = rbase + rg * 16 + lr;
        row = min(row, NN - 1);
        const u16* ap = A + (size_t)row * 128 + lg * 8;
        short8 Af[4];
#pragma unroll
        for (int ks = 0; ks < 4; ++ks) Af[ks] = *(const short8*)(ap + ks * 32);
#pragma unroll
        for (int ks = 0; ks < 4; ++ks)
#pragma unroll
            for (int ct = 0; ct < 4; ++ct)
                acc[rg][ct] = __builtin_amdgcn_mfma_f32_16x16x32_bf16(Af[ks], Bf[ct][ks], acc[rg][ct], 0, 0, 0);
    }

    if (MODE == 2) {
#pragma unroll
        for (int ct = 0; ct < 4; ++ct) {
            float bc = bias[wcol + ct * 16 + lr];
#pragma unroll
            for (int rg = 0; rg < 2; ++rg)
#pragma unroll
                for (int j = 0; j < 4; ++j) acc[rg][ct][j] += bc;
        }
    }

#pragma unroll
    for (int rg = 0; rg < 2; ++rg)
#pragma unroll
        for (int ct = 0; ct < 4; ++ct)
#pragma unroll
            for (int j = 0; j < 4; ++j)
                lC[(wrow + rg * 16 + lg * 4 + j) * 128 + wcol + ct * 16 + lr] = acc[rg][ct][j];
    __syncthreads();

    float cs[4] = {0.f, 0.f, 0.f, 0.f}, cq[4] = {0.f, 0.f, 0.f, 0.f};
#pragma unroll
    for (int i = 0; i < 8; ++i) {
        int eidx = i * 1024 + tid * 4;
        int lrow = eidx >> 7;
        int col = eidx & 127;
        int grow = blockIdx.x * 64 + lrow;
        if (grow < NN) {
            float4 v = *(float4*)(lC + eidx);
            uint2 o = make_uint2(pk(v.x, v.y), pk(v.z, v.w));
            *(uint2*)(Cb + (size_t)grow * 128 + col) = o;
            if (MODE == 2) *(float4*)(Cf + (size_t)grow * 128 + col) = v;
            if (MODE == 1) {
                cs[0] += v.x; cs[1] += v.y; cs[2] += v.z; cs[3] += v.w;
                cq[0] += v.x * v.x; cq[1] += v.y * v.y; cq[2] += v.z * v.z; cq[3] += v.w * v.w;
            }
        }
    }

    if (MODE == 1) {
        __syncthreads();
        int g = tid >> 5, c0 = (tid & 31) * 4;
#pragma unroll
        for (int cc = 0; cc < 4; ++cc) {
            lC[g * 128 + c0 + cc] = cs[cc];
            lC[1024 + g * 128 + c0 + cc] = cq[cc];
        }
        __syncthreads();
        if (tid < 128) {
            float s = 0.f, q = 0.f;
#pragma unroll
            for (int g2 = 0; g2 < 8; ++g2) { s += lC[g2 * 128 + tid]; q += lC[1024 + g2 * 128 + tid]; }
            atomAddG(&sSum[tid], s);
            atomAddG(&sSq[tid], q);
        }
    }
}

// ---------------- BN finalize ----------------
__global__ void k_bnfinal(const float* __restrict__ sSum, const float* __restrict__ sSq,
                          const float* __restrict__ g, const float* __restrict__ be,
                          float* __restrict__ scl, float* __restrict__ shf) {
    int c = threadIdx.x;
    float m = sSum[c] * (1.0f / NN);
    float v = sSq[c] * (1.0f / NN) - m * m;
    float s = g[c] * rsqrtf(v + BN_EPS);
    scl[c] = s;
    shf[c] = be[c] - m * s;
}

// ---------------- in-place BN+ReLU on bf16 buffer ----------------
__global__ void k_bnrelu(u32* __restrict__ tb, const float* __restrict__ scl, const float* __restrict__ shf) {
    int i = blockIdx.x * 256 + threadIdx.x;
    int c0 = (i * 8) & 127;
    uint4 u = *(uint4*)(tb + (size_t)i * 4);
    float4 s0 = *(const float4*)(scl + c0), s1 = *(const float4*)(scl + c0 + 4);
    float4 f0 = *(const float4*)(shf + c0), f1 = *(const float4*)(shf + c0 + 4);
    uint4 o;
    o.x = pk(fmaxf(0.f, bf_lo(u.x) * s0.x + f0.x), fmaxf(0.f, bf_hi(u.x) * s0.y + f0.y));
    o.y = pk(fmaxf(0.f, bf_lo(u.y) * s0.z + f0.z), fmaxf(0.f, bf_hi(u.y) * s0.w + f0.w));
    o.z = pk(fmaxf(0.f, bf_lo(u.z) * s1.x + f1.x), fmaxf(0.f, bf_hi(u.z) * s1.y + f1.y));
    o.w = pk(fmaxf(0.f, bf_lo(u.w) * s1.z + f1.z), fmaxf(0.f, bf_hi(u.w) * s1.w + f1.w));
    *(uint4*)(tb + (size_t)i * 4) = o;
}

// ---------------- CSR pull aggregation: branchless chunk-of-8 batched loads ----------------
// Per chunk: 8 independent eRec loads (clamped idx), then 8 independent row loads,
// then 8 FMAs (tail weights zeroed arithmetically). Two counted-vmcnt stalls per
// chunk instead of 16 serialized full-latency chains.
__global__ __launch_bounds__(256) void k_agg(
    const u32* __restrict__ hwb, const int2* __restrict__ eRec, const int* __restrict__ offs,
    const float* __restrict__ dinv,
    u32* __restrict__ aggb, float* __restrict__ sSum, float* __restrict__ sSq)
{
    int tid = threadIdx.x;
    int lane = tid & 63;
    int wav = tid >> 6;
    int gw = blockIdx.x * 4 + wav;
    int nw = gridDim.x * 4;
    float sx0 = 0.f, sx1 = 0.f, sq0 = 0.f, sq1 = 0.f;

    for (int d = gw; d < NN; d += nw) {
        int j0 = offs[d], j1 = offs[d + 1];
        float ax = 0.f, ay = 0.f;
        for (int jb = j0; jb < j1; jb += 8) {
            int2 r[8];
#pragma unroll
            for (int q = 0; q < 8; ++q)
                r[q] = eRec[min(jb + q, j1 - 1)];
            u32 u[8];
#pragma unroll
            for (int q = 0; q < 8; ++q)
                u[q] = hwb[(size_t)r[q].x * 64 + lane];
#pragma unroll
            for (int q = 0; q < 8; ++q) {
                float wgt = (jb + q < j1) ? __int_as_float(r[q].y) : 0.f;
                ax = fmaf(wgt, bf_lo(u[q]), ax);
                ay = fmaf(wgt, bf_hi(u[q]), ay);
            }
        }
        float dd = dinv[d];
        float vx = ax * dd, vy = ay * dd;
        aggb[(size_t)d * 64 + lane] = pk(vx, vy);
        sx0 += vx; sx1 += vy;
        sq0 += vx * vx; sq1 += vy * vy;
    }

    __shared__ float ls[512], lq[512];
    ls[wav * 128 + lane * 2] = sx0;
    ls[wav * 128 + lane * 2 + 1] = sx1;
    lq[wav * 128 + lane * 2] = sq0;
    lq[wav * 128 + lane * 2 + 1] = sq1;
    __syncthreads();
    if (tid < 128) {
        float s = ls[tid] + ls[tid + 128] + ls[tid + 256] + ls[tid + 384];
        float q = lq[tid] + lq[tid + 128] + lq[tid + 256] + lq[tid + 384];
        atomAddG(&sSum[tid], s);
        atomAddG(&sSq[tid], q);
    }
}

// ---------------- residual update: h += relu(agg*s+f); emit bf16 mirror ----------------
__global__ __launch_bounds__(256) void k_update(
    float* __restrict__ h, const u32* __restrict__ aggb,
    const float* __restrict__ scl, const float* __restrict__ shf,
    u32* __restrict__ hb)
{
    int i = blockIdx.x * 256 + threadIdx.x;
    int c0 = (i * 4) & 127;
    uint2 a = *(const uint2*)(aggb + (size_t)i * 2);
    float4 hv = *(float4*)(h + (size_t)i * 4);
    float4 sv = *(const float4*)(scl + c0);
    float4 fv = *(const float4*)(shf + c0);
    hv.x += fmaxf(0.f, bf_lo(a.x) * sv.x + fv.x);
    hv.y += fmaxf(0.f, bf_hi(a.x) * sv.y + fv.y);
    hv.z += fmaxf(0.f, bf_lo(a.y) * sv.z + fv.z);
    hv.w += fmaxf(0.f, bf_hi(a.y) * sv.w + fv.w);
    *(float4*)(h + (size_t)i * 4) = hv;
    *(uint2*)(hb + (size_t)i * 2) = make_uint2(pk(hv.x, hv.y), pk(hv.z, hv.w));
}

// ---------------- pooling ----------------
__global__ __launch_bounds__(128) void k_pool(const float* __restrict__ h, const int* __restrict__ batch,
                                              float* __restrict__ hg) {
    int c = threadIdx.x;
    int r0 = blockIdx.x * 256;
    int rend = min(r0 + 256, NN);
    float acc = 0.f;
    int cur = batch[r0];
    for (int r = r0; r < rend; ++r) {
        int b = batch[r];
        if (b != cur) { atomAddG(&hg[cur * DD + c], acc); acc = 0.f; cur = b; }
        acc += h[(size_t)r * DD + c];
    }
    atomAddG(&hg[cur * DD + c], acc);
}

// ---------------- readout MLP ----------------
__global__ __launch_bounds__(128) void k_readout(
    const float* __restrict__ hg,
    const float* __restrict__ W1, const float* __restrict__ b1,
    const float* __restrict__ W2, const float* __restrict__ b2,
    const float* __restrict__ W3, const float* __restrict__ b3,
    float* __restrict__ out) {
    __shared__ float a0[128], a1[64], a2[32];
    int g = blockIdx.x, t = threadIdx.x;
    a0[t] = hg[g * DD + t];
    __syncthreads();
    if (t < 64) {
        float s = b1[t];
        for (int k = 0; k < 128; ++k) s += a0[k] * W1[k * 64 + t];
        a1[t] = fmaxf(s, 0.f);
    }
    __syncthreads();
    if (t < 32) {
        float s = b2[t];
        for (int k = 0; k < 64; ++k) s += a1[k] * W2[k * 32 + t];
        a2[t] = fmaxf(s, 0.f);
    }
    __syncthreads();
    if (t == 0) {
        float s = b3[0];
        for (int k = 0; k < 32; ++k) s += a2[k] * W3[k];
        out[g] = s;
    }
}

extern "C" void kernel_launch(void* const* d_in, const int* in_sizes, int n_in,
                              void* d_out, int out_size, void* d_ws, size_t ws_size,
                              hipStream_t stream) {
    const float* x      = (const float*)d_in[0];
    const int*   ei     = (const int*)d_in[1];
    const int*   batch  = (const int*)d_in[2];
    const float* enc_W1 = (const float*)d_in[3];
    const float* enc_g  = (const float*)d_in[5];
    const float* enc_be = (const float*)d_in[6];
    const float* enc_W2 = (const float*)d_in[7];
    const float* enc_b2 = (const float*)d_in[8];
    const float* conv_W = (const float*)d_in[9];
    // d_in[4]=enc_b1, d_in[10]=conv_b: dead (additive pre-BN bias cancels in BN)
    const float* bn_g   = (const float*)d_in[11];
    const float* bn_b   = (const float*)d_in[12];
    const float* ro_W1  = (const float*)d_in[13];
    const float* ro_b1  = (const float*)d_in[14];
    const float* ro_W2  = (const float*)d_in[15];
    const float* ro_b2  = (const float*)d_in[16];
    const float* ro_W3  = (const float*)d_in[17];
    const float* ro_b3  = (const float*)d_in[18];

    const int* srcI = ei;
    const int* dstI = ei + NE;

    float* ws   = (float*)d_ws;
    float* h    = ws;                          // [NN*DD] f32
    u32*   aggb = (u32*)(ws + 12800000);       // [NN*64] u32 (bf16x2) — aliases encoder tb
    u32*   hb   = (u32*)(ws + 19200000);       // [NN*64] u32
    u32*   t1b  = (u32*)(ws + 25600000);       // [NN*64] u32 — aliases xb
    u16*   wtb  = (u16*)(ws + 32000000);       // 5*16384 bf16
    float* dinv = ws + 32050000;               // [NN]
    float* sSum = ws + 32150000;               // 128
    float* sSq  = sSum + 128;
    float* scl  = sSum + 256;
    float* shf  = sSum + 384;
    float* hg   = ws + 32150512;               // [NG*DD]
    int*   offs = (int*)(ws + 32160000);       // [NN+1]
    int*   degI = (int*)(ws + 32270000);       // [NN]
    int*   bsum = (int*)(ws + 32370000);       // [512]
    int2*  eRec = (int2*)(ws + 32380000);      // [NE]

    u16* tb16 = (u16*)aggb;
    u16* xb16 = (u16*)t1b;

    // ---- prep ----
    k_prepW<<<40, 256, 0, stream>>>(enc_W1, enc_W2, conv_W, wtb);
    k_prepX<<<6250, 256, 0, stream>>>(x, (u32*)xb16);

    // ---- CSR build ----
    hipMemsetAsync(degI, 0, NN * sizeof(int), stream);
    k_degI<<<2500, 256, 0, stream>>>(dstI, degI);
    k_dinv<<<391, 256, 0, stream>>>(degI, dinv);
    k_scan1<<<391, 256, 0, stream>>>(degI, offs, bsum);
    k_scan2<<<1, 512, 0, stream>>>(bsum, 391);
    k_scan3<<<391, 256, 0, stream>>>(offs, bsum);
    hipMemsetAsync(degI, 0, NN * sizeof(int), stream);
    k_place<<<2500, 256, 0, stream>>>(srcI, dstI, offs, degI, dinv, eRec);

    // ---- encoder ----
    hipMemsetAsync(sSum, 0, 256 * sizeof(float), stream);
    k_mm<1><<<1563, 256, 0, stream>>>(xb16, wtb, nullptr, tb16, nullptr, sSum, sSq);
    k_bnfinal<<<1, 128, 0, stream>>>(sSum, sSq, enc_g, enc_be, scl, shf);
    k_bnrelu<<<6250, 256, 0, stream>>>((u32*)tb16, scl, shf);
    k_mm<2><<<1563, 256, 0, stream>>>(tb16, wtb + 16384, enc_b2, (u16*)hb, h, nullptr, nullptr);

    // ---- GCN layers ----
    for (int l = 0; l < NL; ++l) {
        k_mm<0><<<1563, 256, 0, stream>>>((const u16*)hb, wtb + (size_t)(2 + l) * 16384, nullptr,
                                          (u16*)t1b, nullptr, nullptr, nullptr);
        hipMemsetAsync(sSum, 0, 256 * sizeof(float), stream);
        k_agg<<<2048, 256, 0, stream>>>(t1b, eRec, offs, dinv, aggb, sSum, sSq);
        k_bnfinal<<<1, 128, 0, stream>>>(sSum, sSq, bn_g + l * DD, bn_b + l * DD, scl, shf);
        k_update<<<12500, 256, 0, stream>>>(h, aggb, scl, shf, hb);
    }

    // ---- pooling + readout ----
    hipMemsetAsync(hg, 0, NG * DD * sizeof(float), stream);
    k_pool<<<391, 128, 0, stream>>>(h, batch, hg);
    k_readout<<<NG, 128, 0, stream>>>(hg, ro_W1, ro_b1, ro_W2, ro_b2, ro_W3, ro_b3, (float*)d_out);
}